// Round 5
// baseline (44.971 us; speedup 1.0000x reference)
//
#include <hip/hip_runtime.h>
#include <hip/hip_bf16.h>

// N=4096, M=128, R=16, W=64, NG=1024, delta = 1/128 exactly.
// out[n,r,w] = sum_m red[n,r,m] * (c4[idx[n,m],w]*x0 + c5[idx[n,m],w])
// degree-1 truncation (x0 < 1/128) + bf16 MFMA, barrier-free wave-independent blocks.

constexpr int MM = 128;
constexpr int RR = 16;
constexpr int WW = 64;
constexpr int NG = 1024;

using f32x4  = __attribute__((ext_vector_type(4))) float;
using bf16x8 = __attribute__((ext_vector_type(8))) __bf16;

__device__ __forceinline__ unsigned pack_bf16(float lo, float hi) {
    __hip_bfloat162 p = __float22bfloat162_rn(make_float2(lo, hi));
    unsigned r; __builtin_memcpy(&r, &p, sizeof(r));   // v_cvt_pk_bf16_f32
    return r;
}

// ---- prepass: tbl[g*64 + w] = (bf16(c5[g][w])<<16) | bf16(c4[g][w]) ----
__global__ __launch_bounds__(256)
void build_tbl_kernel(const float* __restrict__ poly, unsigned* __restrict__ tbl) {
    const int t = blockIdx.x * 256 + threadIdx.x;   // 65536
    const int g = t >> 6, w = t & 63;
    tbl[t] = pack_bf16(poly[g * 384 + 256 + w], poly[g * 384 + 320 + w]);
}

// Wave-independent: wave wt of block n computes out[n][0:16][wt*16 .. +16].
// eT tile per wave: [16 rows(w)][64 u32 m-pairs], col ^= (row&7)<<2 swizzle.
// No __syncthreads anywhere.
template<bool USE_TBL>
__global__ __launch_bounds__(256, 4)
void embed_mfma_kernel(const float* __restrict__ x,
                       const unsigned* __restrict__ tbl,
                       const float* __restrict__ poly,
                       const float* __restrict__ red,
                       float* __restrict__ out)
{
    __shared__ __align__(16) unsigned eT[4][16][64];   // 16 KB

    const int n    = blockIdx.x;
    const int t    = threadIdx.x;
    const int l    = t & 63;
    const int wt   = t >> 6;
    const int rowa = l & 15;   // r for A, w-within-tile for B/D
    const int kq   = l >> 4;   // 0..3

    // ---- x for this lane's two m's (m = 2l, 2l+1) ----
    const float2 xv = *(const float2*)(x + (size_t)n * MM + 2 * l);

    // ---- red straight to A-fragment lanes: red[n][rowa][kq*8 + kc*32 + 0..7] ----
    const float* rp = red + (size_t)n * (RR * MM) + rowa * MM + kq * 8;
    float4 rf[8];
#pragma unroll
    for (int kc = 0; kc < 4; ++kc) {
        rf[2 * kc]     = *(const float4*)(rp + kc * 32);
        rf[2 * kc + 1] = *(const float4*)(rp + kc * 32 + 4);
    }

    // ---- gather setup (depends only on x) ----
    const int   i0 = (int)(xv.x * 128.0f);
    const int   i1 = (int)(xv.y * 128.0f);
    const float x0 = xv.x - (float)i0 * 0.0078125f;
    const float x1 = xv.y - (float)i1 * 0.0078125f;

    uint4 af4[4];      // A fragments (bf16x8 per kc)
    unsigned ep[16];   // packed embed (m=2l, 2l+1) for w = wt*16 + j

    if (USE_TBL) {
        const uint4* t0 = (const uint4*)(tbl + i0 * 64 + wt * 16);
        const uint4* t1 = (const uint4*)(tbl + i1 * 64 + wt * 16);
        uint4 u0[4], u1[4];
#pragma unroll
        for (int j = 0; j < 4; ++j) u0[j] = t0[j];
#pragma unroll
        for (int j = 0; j < 4; ++j) u1[j] = t1[j];

        // pack A while gathers are in flight
#pragma unroll
        for (int kc = 0; kc < 4; ++kc) {
            af4[kc].x = pack_bf16(rf[2 * kc].x,     rf[2 * kc].y);
            af4[kc].y = pack_bf16(rf[2 * kc].z,     rf[2 * kc].w);
            af4[kc].z = pack_bf16(rf[2 * kc + 1].x, rf[2 * kc + 1].y);
            af4[kc].w = pack_bf16(rf[2 * kc + 1].z, rf[2 * kc + 1].w);
        }

#pragma unroll
        for (int j = 0; j < 4; ++j) {
            const unsigned uu0[4] = {u0[j].x, u0[j].y, u0[j].z, u0[j].w};
            const unsigned uu1[4] = {u1[j].x, u1[j].y, u1[j].z, u1[j].w};
#pragma unroll
            for (int c = 0; c < 4; ++c) {
                const float a4 = __uint_as_float(uu0[c] << 16);
                const float a5 = __uint_as_float(uu0[c] & 0xFFFF0000u);
                const float b4 = __uint_as_float(uu1[c] << 16);
                const float b5 = __uint_as_float(uu1[c] & 0xFFFF0000u);
                ep[j * 4 + c] = pack_bf16(fmaf(a4, x0, a5), fmaf(b4, x1, b5));
            }
        }
    } else {
        const float* p0 = poly + (size_t)i0 * 384 + 256 + wt * 16;
        const float* p1 = poly + (size_t)i1 * 384 + 256 + wt * 16;
#pragma unroll
        for (int kc = 0; kc < 4; ++kc) {
            af4[kc].x = pack_bf16(rf[2 * kc].x,     rf[2 * kc].y);
            af4[kc].y = pack_bf16(rf[2 * kc].z,     rf[2 * kc].w);
            af4[kc].z = pack_bf16(rf[2 * kc + 1].x, rf[2 * kc + 1].y);
            af4[kc].w = pack_bf16(rf[2 * kc + 1].z, rf[2 * kc + 1].w);
        }
#pragma unroll
        for (int j = 0; j < 4; ++j) {
            const float4 a4 = *(const float4*)(p0 + 4 * j);
            const float4 a5 = *(const float4*)(p0 + 64 + 4 * j);
            const float4 b4 = *(const float4*)(p1 + 4 * j);
            const float4 b5 = *(const float4*)(p1 + 64 + 4 * j);
            ep[j * 4 + 0] = pack_bf16(fmaf(a4.x, x0, a5.x), fmaf(b4.x, x1, b5.x));
            ep[j * 4 + 1] = pack_bf16(fmaf(a4.y, x0, a5.y), fmaf(b4.y, x1, b5.y));
            ep[j * 4 + 2] = pack_bf16(fmaf(a4.z, x0, a5.z), fmaf(b4.z, x1, b5.z));
            ep[j * 4 + 3] = pack_bf16(fmaf(a4.w, x0, a5.w), fmaf(b4.w, x1, b5.w));
        }
    }

    // ---- eT write: row j, u32-col l, swizzled; this wave is the only reader ----
#pragma unroll
    for (int j = 0; j < 16; ++j)
        eT[wt][j][l ^ ((j & 7) << 2)] = ep[j];

    __builtin_amdgcn_wave_barrier();   // pin ds_write -> ds_read order at compile time

    // ---- MFMA: 4 chained 16x16x32 over K=128 ----
    const uint4* bt = (const uint4*)&eT[wt][rowa][0];
    f32x4 acc = {0.f, 0.f, 0.f, 0.f};
#pragma unroll
    for (int kc = 0; kc < 4; ++kc) {
        const uint4 bv = bt[(kc * 4 + kq) ^ (rowa & 7)];
        const bf16x8 afr = __builtin_bit_cast(bf16x8, af4[kc]);
        const bf16x8 bfr = __builtin_bit_cast(bf16x8, bv);
        acc = __builtin_amdgcn_mfma_f32_16x16x32_bf16(afr, bfr, acc, 0, 0, 0);
    }

    // C/D layout: col = lane&15 (w), row = kq*4 + reg (r)
    float* op = out + (size_t)n * (RR * WW) + (size_t)(kq * 4) * WW + wt * 16 + rowa;
    op[0 * WW] = acc[0];
    op[1 * WW] = acc[1];
    op[2 * WW] = acc[2];
    op[3 * WW] = acc[3];
}

extern "C" void kernel_launch(void* const* d_in, const int* in_sizes, int n_in,
                              void* d_out, int out_size, void* d_ws, size_t ws_size,
                              hipStream_t stream) {
    const float* x    = (const float*)d_in[0];
    const float* poly = (const float*)d_in[1];
    const float* red  = (const float*)d_in[2];
    float* out = (float*)d_out;
    const int N = in_sizes[0] / MM;   // 4096

    if (ws_size >= (size_t)(NG * WW * sizeof(unsigned))) {
        unsigned* tbl = (unsigned*)d_ws;
        build_tbl_kernel<<<(NG * WW) / 256, 256, 0, stream>>>(poly, tbl);
        embed_mfma_kernel<true><<<N, 256, 0, stream>>>(x, tbl, poly, red, out);
    } else {
        embed_mfma_kernel<false><<<N, 256, 0, stream>>>(x, nullptr, poly, red, out);
    }
}

// Round 6
// 23.803 us; speedup vs baseline: 1.8893x; 1.8893x over previous
//
#include <hip/hip_runtime.h>
#include <hip/hip_bf16.h>

// N=4096, M=128, R=16, W=64, NG=1024, delta = 1/128 exactly.
// out[n,r,w] = sum_m red[n,r,m] * (c4[idx[n,m],w]*x0 + c5[idx[n,m],w])
// Degree-1 truncation + bf16 MFMA. Key fix this round: COALESCED tbl gather
// (16 contiguous lanes read contiguous 16B slices of the same tbl row ->
// 8 cache-line requests per wave instruction instead of 64).

constexpr int MM = 128;
constexpr int RR = 16;
constexpr int WW = 64;
constexpr int NG = 1024;

using f32x4  = __attribute__((ext_vector_type(4))) float;
using bf16x8 = __attribute__((ext_vector_type(8))) __bf16;

__device__ __forceinline__ unsigned pack_bf16(float lo, float hi) {
    __hip_bfloat162 p = __float22bfloat162_rn(make_float2(lo, hi));
    unsigned r; __builtin_memcpy(&r, &p, sizeof(r));   // v_cvt_pk_bf16_f32
    return r;
}

// ---- prepass: tbl[g*64 + w] = (bf16(c5)<<16) | bf16(c4) ----
__global__ __launch_bounds__(256)
void build_tbl_kernel(const float* __restrict__ poly, unsigned* __restrict__ tbl) {
    const int t = blockIdx.x * 256 + threadIdx.x;   // 65536
    const int g = t >> 6, w = t & 63;
    tbl[t] = pack_bf16(poly[g * 384 + 256 + w], poly[g * 384 + 320 + w]);
}

template<bool USE_TBL>
__global__ __launch_bounds__(256, 4)
void embed_mfma_kernel(const float* __restrict__ x,
                       const unsigned* __restrict__ tbl,
                       const float* __restrict__ poly,
                       const float* __restrict__ red,
                       float* __restrict__ out)
{
    // eT4[w][b]: m-block b (8 bf16, m = 8b..8b+7) of embed^T row w, b XOR (w&7).
    // rA4[r][b]: same for red row r, b XOR (r&7).
    __shared__ uint4 eT4[WW][16];   // 16 KB
    __shared__ uint4 rA4[RR][16];   //  4 KB

    const int n    = blockIdx.x;
    const int t    = threadIdx.x;
    const int l    = t & 63;
    const int wt   = t >> 6;
    const int q    = l >> 4;    // 0..3
    const int c16  = l & 15;    // 16-lane sub-id

    // ---- red -> registers (fully coalesced, issued first) ----
    const float4* rv = (const float4*)(red + (size_t)n * (RR * MM));
    const float4 ra = rv[2 * t];
    const float4 rb = rv[2 * t + 1];

    // ---- x for this lane's 8 contiguous m's: m = wt*32 + q*8 + j ----
    const int mb = wt * 32 + q * 8;
    const float* xp = x + (size_t)n * MM + mb;
    const float4 xv0 = *(const float4*)xp;
    const float4 xv1 = *(const float4*)(xp + 4);

    const float xs[8] = {xv0.x, xv0.y, xv0.z, xv0.w, xv1.x, xv1.y, xv1.z, xv1.w};
    int ii[8]; float x0[8];
#pragma unroll
    for (int j = 0; j < 8; ++j) {
        ii[j] = (int)(xs[j] * 128.0f);
        x0[j] = xs[j] - (float)ii[j] * 0.0078125f;
    }

    unsigned bw[4][4];   // bw[c][jp]: packed bf16 pair (m=2jp, 2jp+1) for w = c16*4+c

    if (USE_TBL) {
        // coalesced gather: 16 lanes read contiguous 256B of one tbl row
        uint4 g[8];
#pragma unroll
        for (int j = 0; j < 8; ++j)
            g[j] = *(const uint4*)(tbl + (size_t)ii[j] * 64 + c16 * 4);

        // stage rA while gathers are in flight
        {
            const int rr = t >> 4, mbk = t & 15;
            uint4 rp;
            rp.x = pack_bf16(ra.x, ra.y); rp.y = pack_bf16(ra.z, ra.w);
            rp.z = pack_bf16(rb.x, rb.y); rp.w = pack_bf16(rb.z, rb.w);
            rA4[rr][mbk ^ (rr & 7)] = rp;
        }

#pragma unroll
        for (int jp = 0; jp < 4; ++jp) {
            const unsigned ga[4] = {g[2*jp].x,   g[2*jp].y,   g[2*jp].z,   g[2*jp].w};
            const unsigned gb[4] = {g[2*jp+1].x, g[2*jp+1].y, g[2*jp+1].z, g[2*jp+1].w};
#pragma unroll
            for (int c = 0; c < 4; ++c) {
                const float e0 = fmaf(__uint_as_float(ga[c] << 16), x0[2*jp],
                                      __uint_as_float(ga[c] & 0xFFFF0000u));
                const float e1 = fmaf(__uint_as_float(gb[c] << 16), x0[2*jp+1],
                                      __uint_as_float(gb[c] & 0xFFFF0000u));
                bw[c][jp] = pack_bf16(e0, e1);
            }
        }
    } else {
        {
            const int rr = t >> 4, mbk = t & 15;
            uint4 rp;
            rp.x = pack_bf16(ra.x, ra.y); rp.y = pack_bf16(ra.z, ra.w);
            rp.z = pack_bf16(rb.x, rb.y); rp.w = pack_bf16(rb.z, rb.w);
            rA4[rr][mbk ^ (rr & 7)] = rp;
        }
#pragma unroll
        for (int jp = 0; jp < 4; ++jp) {
            const float* pa = poly + (size_t)ii[2*jp]   * 384 + c16 * 4;
            const float* pb = poly + (size_t)ii[2*jp+1] * 384 + c16 * 4;
            const float4 a4 = *(const float4*)(pa + 256);
            const float4 a5 = *(const float4*)(pa + 320);
            const float4 b4 = *(const float4*)(pb + 256);
            const float4 b5 = *(const float4*)(pb + 320);
            const float a4_[4] = {a4.x, a4.y, a4.z, a4.w};
            const float a5_[4] = {a5.x, a5.y, a5.z, a5.w};
            const float b4_[4] = {b4.x, b4.y, b4.z, b4.w};
            const float b5_[4] = {b5.x, b5.y, b5.z, b5.w};
#pragma unroll
            for (int c = 0; c < 4; ++c) {
                const float e0 = fmaf(a4_[c], x0[2*jp],   a5_[c]);
                const float e1 = fmaf(b4_[c], x0[2*jp+1], b5_[c]);
                bw[c][jp] = pack_bf16(e0, e1);
            }
        }
    }

    // ---- write eT: lane owns m-block (wt*4+q) of rows w = c16*4 + 0..3 ----
#pragma unroll
    for (int c = 0; c < 4; ++c) {
        const int w = c16 * 4 + c;
        uint4 v; v.x = bw[c][0]; v.y = bw[c][1]; v.z = bw[c][2]; v.w = bw[c][3];
        eT4[w][(wt * 4 + q) ^ (w & 7)] = v;
    }

    __syncthreads();

    // ---- MFMA: wave wt computes out[n][0:16][wt*16 .. +16] ----
    const int rowa = c16;            // r for A, w-within-tile for B/D
    const int kq   = q;
    const int rowb = wt * 16 + rowa;

    f32x4 acc = {0.f, 0.f, 0.f, 0.f};
#pragma unroll
    for (int kc = 0; kc < 4; ++kc) {
        const uint4 av = rA4[rowa][(kc * 4 + kq) ^ (rowa & 7)];
        const uint4 bv = eT4[rowb][(kc * 4 + kq) ^ (rowa & 7)];
        const bf16x8 afr = __builtin_bit_cast(bf16x8, av);
        const bf16x8 bfr = __builtin_bit_cast(bf16x8, bv);
        acc = __builtin_amdgcn_mfma_f32_16x16x32_bf16(afr, bfr, acc, 0, 0, 0);
    }

    // C/D layout: col = lane&15 (w), row = kq*4 + reg (r)
    float* op = out + (size_t)n * (RR * WW) + (size_t)(kq * 4) * WW + rowb;
    op[0 * WW] = acc[0];
    op[1 * WW] = acc[1];
    op[2 * WW] = acc[2];
    op[3 * WW] = acc[3];
}

extern "C" void kernel_launch(void* const* d_in, const int* in_sizes, int n_in,
                              void* d_out, int out_size, void* d_ws, size_t ws_size,
                              hipStream_t stream) {
    const float* x    = (const float*)d_in[0];
    const float* poly = (const float*)d_in[1];
    const float* red  = (const float*)d_in[2];
    float* out = (float*)d_out;
    const int N = in_sizes[0] / MM;   // 4096

    if (ws_size >= (size_t)(NG * WW * sizeof(unsigned))) {
        unsigned* tbl = (unsigned*)d_ws;
        build_tbl_kernel<<<(NG * WW) / 256, 256, 0, stream>>>(poly, tbl);
        embed_mfma_kernel<true><<<N, 256, 0, stream>>>(x, tbl, poly, red, out);
    } else {
        embed_mfma_kernel<false><<<N, 256, 0, stream>>>(x, nullptr, poly, red, out);
    }
}